// Round 10
// baseline (324.299 us; speedup 1.0000x reference)
//
#include <hip/hip_runtime.h>

typedef __attribute__((ext_vector_type(8))) short bf16x8;
typedef __attribute__((ext_vector_type(4))) float f32x4;
typedef __attribute__((ext_vector_type(4))) float f32x4v;
typedef __attribute__((ext_vector_type(4))) int i32x4;

#define MFMA16(a,b,c) __builtin_amdgcn_mfma_f32_16x16x32_bf16((a),(b),(c),0,0,0)

__device__ __forceinline__ short f2bf(float f){
  unsigned u = __builtin_bit_cast(unsigned, f);
  u += 0x7fffu + ((u >> 16) & 1u);   // round-to-nearest-even
  return (short)(u >> 16);
}

__device__ __forceinline__ void gload16(const void* g, void* l){
  __builtin_amdgcn_global_load_lds((const __attribute__((address_space(1))) unsigned*)g,
                                   (__attribute__((address_space(3))) unsigned*)l,
                                   16, 0, 0);
}

// pack hi16 of two f32 (with rounding) into one dword: [lo16=a, hi16=b]
__device__ __forceinline__ int packbf(float a, float b){
  unsigned ua = __builtin_bit_cast(unsigned, a) + 0x7fffu;
  unsigned ub = __builtin_bit_cast(unsigned, b) + 0x7fffu;
  return __builtin_amdgcn_perm(ub, ua, 0x07060302);  // bytes: ua[3:2], ub[3:2]
}

// ---------------- fp32 -> bf16 elementwise convert (vectorized) ----------------
__global__ __launch_bounds__(256) void k_f2bf(const float* __restrict__ in,
                                              short* __restrict__ out, int n8){
  int i = blockIdx.x * 256 + threadIdx.x;
  if (i >= n8) return;
  f32x4v a = ((const f32x4v*)in)[i*2];
  f32x4v b = ((const f32x4v*)in)[i*2+1];
  bf16x8 o;
  o[0]=f2bf(a[0]); o[1]=f2bf(a[1]); o[2]=f2bf(a[2]); o[3]=f2bf(a[3]);
  o[4]=f2bf(b[0]); o[5]=f2bf(b[1]); o[6]=f2bf(b[2]); o[7]=f2bf(b[3]);
  ((bf16x8*)out)[i] = o;
}

// ---------------- weight transpose + convert: Wt[n][k] = bf16(W[k][n]) ----------------
__global__ __launch_bounds__(256) void k_prep_wT(const float* __restrict__ W,
                                                 short* __restrict__ Wt, int K, int N){
  int i = blockIdx.x * 256 + threadIdx.x;
  int total = (K >> 3) * N;
  if (i >= total) return;
  int n  = i % N;
  int k0 = (i / N) << 3;
  bf16x8 o;
#pragma unroll
  for (int j = 0; j < 8; ++j) o[j] = f2bf(W[(size_t)(k0 + j) * N + n]);
  *(bf16x8*)&Wt[(size_t)n * K + k0] = o;
}

// ---------------- 128x128-tile bf16 GEMM, tri-buffered, counted vmcnt (R5-exact) ----
template<int MODE>
__global__ __launch_bounds__(256, 4) void k_gemm(
    const short* __restrict__ A, const short* __restrict__ Bt,
    const float* __restrict__ bias, float scale,
    void* __restrict__ out0, void* __restrict__ out1,
    int M, int N, int K)
{
  __shared__ __align__(16) short Alds[3][128 * 32];
  __shared__ __align__(16) short Blds[3][128 * 32];
  const int tid = threadIdx.x;
  const int l = tid & 63, w = tid >> 6;
  const int wr = w >> 1, wc = w & 1;
  const int lr = l & 15, lg = l >> 4;

  const int nx = gridDim.x;
  const int nwg = nx * gridDim.y;
  int flat = blockIdx.y * nx + blockIdx.x;
  int u = (flat & 7) * (nwg >> 3) + (flat >> 3);
  const int m0 = (u / nx) * 128, n0 = (u % nx) * 128;

  const int srow = l >> 2;
  const int scol = 8 * ((l & 3) ^ ((l >> 3) & 3));
  const int acol = 8 * (lg ^ ((lr >> 1) & 3));

  f32x4 acc[4][4];
#pragma unroll
  for (int a = 0; a < 4; ++a)
#pragma unroll
    for (int b = 0; b < 4; ++b) acc[a][b] = (f32x4)(0.0f);

  const int nk = K >> 5;
  auto stage = [&](int kt, int slot){
    int k0 = kt << 5;
#pragma unroll
    for (int i = 0; i < 4; ++i){
      int c = w * 4 + i;
      if (c < 8){
        int m = c * 16 + srow;
        gload16(A + (size_t)(m0 + m) * K + k0 + scol, &Alds[slot][c * 512]);
      } else {
        int n = (c - 8) * 16 + srow;
        gload16(Bt + (size_t)(n0 + n) * K + k0 + scol, &Blds[slot][(c - 8) * 512]);
      }
    }
  };

  stage(0, 0);
  stage(1, 1);
  int rd = 0;
  for (int kt = 0; kt < nk; ++kt){
    asm volatile("s_waitcnt vmcnt(4)" ::: "memory");
    __builtin_amdgcn_s_barrier();
    __builtin_amdgcn_sched_barrier(0);
    int tt = (kt + 2 < nk) ? kt + 2 : nk - 1;
    int tgt = rd + 2; if (tgt >= 3) tgt -= 3;
    stage(tt, tgt);

    bf16x8 af[4], bfv[4];
#pragma unroll
    for (int mi = 0; mi < 4; ++mi){
      int row = wr * 64 + mi * 16 + lr;
      af[mi] = *(const bf16x8*)&Alds[rd][row * 32 + acol];
    }
#pragma unroll
    for (int ni = 0; ni < 4; ++ni){
      int row = wc * 64 + ni * 16 + lr;
      bfv[ni] = *(const bf16x8*)&Blds[rd][row * 32 + acol];
    }
#pragma unroll
    for (int mi = 0; mi < 4; ++mi)
#pragma unroll
      for (int ni = 0; ni < 4; ++ni)
        acc[mi][ni] = MFMA16(af[mi], bfv[ni], acc[mi][ni]);

    if (++rd == 3) rd = 0;
  }
  asm volatile("s_waitcnt vmcnt(0)" ::: "memory");

#pragma unroll
  for (int mi = 0; mi < 4; ++mi)
#pragma unroll
    for (int ni = 0; ni < 4; ++ni){
      int col = n0 + wc * 64 + ni * 16 + lr;
      float bv = bias[col];
#pragma unroll
      for (int r = 0; r < 4; ++r){
        int row = m0 + wr * 64 + mi * 16 + lg * 4 + r;
        float v = acc[mi][ni][r] + bv;
        if (MODE == 0){
          v *= scale;
          int b = row >> 10, lp = row & 1023;
          int h = lp >> 7;
          int lq = ((lp & 127) << 3) | (col >> 7);
          int dh = col & 127;
          ((short*)out0)[(((size_t)(b * 8 + h)) * 1024 + lq) * 128 + dh] = f2bf(v);
        } else {
          ((float*)out0)[(size_t)row * N + col] = v;
        }
      }
    }
}

// ---------------- KV GEMM: 256x256, 8 waves, tri-buffered (R8 structure) ------------
// NEW: n-panel-per-XCD remap — each XCD owns one 256-col weight panel (512KB, L2-resident)
__global__ __launch_bounds__(512, 2) void k_gemmKV(
    const short* __restrict__ A, const short* __restrict__ Bt,
    const float* __restrict__ bias,
    short* __restrict__ out0, short* __restrict__ out1)
{
  __shared__ __align__(16) short As[3][256 * 32];
  __shared__ __align__(16) short Bs[3][256 * 32];
  const int tid = threadIdx.x;
  const int l = tid & 63, w = tid >> 6;
  const int lr = l & 15, lg = l >> 4;
  const int wm = w >> 2, wn = w & 3;

  // n-panel per XCD: xcd owns n0 = xcd*256 for all 64 m-tiles (bijective, nwg=512)
  int flat = blockIdx.y * 8 + blockIdx.x;
  const int m0 = (flat >> 3) * 256, n0 = (flat & 7) * 256;

  const int srow = l >> 2;
  const int scol = 8 * ((l & 3) ^ ((l >> 3) & 3));
  const int acol = 8 * (lg ^ ((lr >> 1) & 3));

  f32x4 acc[8][4];
#pragma unroll
  for (int a = 0; a < 8; ++a)
#pragma unroll
    for (int b = 0; b < 4; ++b) acc[a][b] = (f32x4)(0.0f);

  auto stage = [&](int kt, int slot){
    int k0 = kt << 5;
#pragma unroll
    for (int i = 0; i < 4; ++i){
      int c = w * 4 + i;
      if (c < 16){
        int m = c * 16 + srow;
        gload16(A + (size_t)(m0 + m) * 1024 + k0 + scol, &As[slot][c * 512]);
      } else {
        int n = (c - 16) * 16 + srow;
        gload16(Bt + (size_t)(n0 + n) * 1024 + k0 + scol, &Bs[slot][(c - 16) * 512]);
      }
    }
  };

  stage(0, 0);
  stage(1, 1);
  int rd = 0;
  for (int kt = 0; kt < 32; ++kt){
    asm volatile("s_waitcnt vmcnt(4)" ::: "memory");
    __builtin_amdgcn_s_barrier();
    __builtin_amdgcn_sched_barrier(0);
    int tt = (kt + 2 < 32) ? kt + 2 : 31;
    int tgt = rd + 2; if (tgt >= 3) tgt -= 3;
    stage(tt, tgt);

    bf16x8 af[8], bfv[4];
#pragma unroll
    for (int mi = 0; mi < 8; ++mi){
      int row = wm * 128 + mi * 16 + lr;
      af[mi] = *(const bf16x8*)&As[rd][row * 32 + acol];
    }
#pragma unroll
    for (int ni = 0; ni < 4; ++ni){
      int row = wn * 64 + ni * 16 + lr;
      bfv[ni] = *(const bf16x8*)&Bs[rd][row * 32 + acol];
    }
    __builtin_amdgcn_s_setprio(1);
#pragma unroll
    for (int mi = 0; mi < 8; ++mi)
#pragma unroll
      for (int ni = 0; ni < 4; ++ni)
        acc[mi][ni] = MFMA16(af[mi], bfv[ni], acc[mi][ni]);
    __builtin_amdgcn_s_setprio(0);

    if (++rd == 3) rd = 0;
  }
  asm volatile("s_waitcnt vmcnt(0)" ::: "memory");

#pragma unroll
  for (int mi = 0; mi < 8; ++mi)
#pragma unroll
    for (int ni = 0; ni < 4; ++ni){
      int col = n0 + wn * 64 + ni * 16 + lr;
      float bv = bias[col];
#pragma unroll
      for (int r = 0; r < 4; ++r){
        int row = m0 + wm * 128 + mi * 16 + lg * 4 + r;
        float v = acc[mi][ni][r] + bv;
        int b = row >> 11, nn = row & 2047;
        if (col < 1024){
          int h = col >> 7, dh = col & 127;
          out0[(((size_t)(b * 8 + h)) * 2048 + nn) * 128 + dh] = f2bf(v);
        } else {
          int c2 = col - 1024, h = c2 >> 7, dh = c2 & 127;
          out1[(((size_t)(b * 8 + h)) * 128 + dh) * 2048 + nn] = f2bf(v);
        }
      }
    }
}

// ---------------- flash attention: 64-q blocks, KVBLK=32, 4 blocks/CU ----------------
// Swapped QK^T + in-register P (R8 technique). 4 waves x 16 q; grid 1024 -> 4 waves/SIMD.
// S = mfma(K,Q): lane holds P[q=lr][key=nt*16+lg*4+r], nt in {0,1}.
// Exchange to PV A-layout: dword dw <- lane lr+16*((2lg+(dw>>1))&3), reg pk[lg>>1][dw&1].
__global__ __launch_bounds__(256, 4) void k_attn(
    const short* __restrict__ Q, const short* __restrict__ K,
    const short* __restrict__ Vt, short* __restrict__ O)
{
  __shared__ __align__(16) short Klds[2][32 * 128];   // [key][dh^swz], 8KB each
  __shared__ __align__(16) short Vlds[2][128 * 32];   // [dh][key^swz], 8KB each
  const int tid = threadIdx.x;                        // total LDS = 32KB
  const int l = tid & 63, w = tid >> 6;
  const int lr = l & 15, lg = l >> 4;

  // XCD-chunked: grid (8,128) = 1024 blocks; xcd owns 8 consecutive bh
  int flat = blockIdx.y * 8 + blockIdx.x;
  int xcd = flat & 7, idx = flat >> 3;          // idx in [0,128)
  int bh = xcd * 8 + (idx >> 4);
  int q0 = (idx & 15) * 64;
  const int qbase = q0 + w * 16;

  const short* Qb = Q  + (size_t)bh * 1024 * 128;
  const short* Kb = K  + (size_t)bh * 2048 * 128;
  const short* Vb = Vt + (size_t)bh * 128 * 2048;

  // Q fragments (B operand): col=q=lr, k = kc*32 + lg*8 + e
  bf16x8 qf[4];
#pragma unroll
  for (int kc = 0; kc < 4; ++kc)
    qf[kc] = *(const bf16x8*)&Qb[(size_t)(qbase + lr) * 128 + kc * 32 + lg * 8];

  f32x4 acc[8];
#pragma unroll
  for (int d = 0; d < 8; ++d) acc[d] = (f32x4)(0.0f);
  float mrun = -3e38f, lsum = 0.f;

  // staging: pre-swizzled global source + linear LDS dest
  // K: 8 chunks of 1KB (4 rows x 128 elems); V: 8 chunks (16 dh x 32 elems)
  auto stageK = [&](int t, int buf){
    int kv0 = t * 32;
#pragma unroll
    for (int i = 0; i < 2; ++i){
      int c = w * 2 + i;
      int row = 4 * c + (l >> 4);
      int col = ((l & 15) * 8) ^ ((row & 7) * 8);
      gload16(Kb + (size_t)(kv0 + row) * 128 + col, &Klds[buf][c * 512]);
    }
  };
  auto stageV = [&](int t, int buf){
    int kv0 = t * 32;
#pragma unroll
    for (int i = 0; i < 2; ++i){
      int c = w * 2 + i;
      int dh = c * 16 + (l >> 2);
      int col = ((l & 3) * 8) ^ (((l >> 2) & 3) * 8);
      gload16(Vb + (size_t)dh * 2048 + kv0 + col, &Vlds[buf][c * 512]);
    }
  };

  stageK(0, 0); stageV(0, 0);
  __syncthreads();
  int cur = 0;
  const int kswz = (lr & 7) * 8;
  const int vswz = (lr & 3) * 8;

  for (int t = 0; t < 64; ++t){
    if (t + 1 < 64){ stageK(t + 1, cur ^ 1); stageV(t + 1, cur ^ 1); }
    const short* Kl = &Klds[cur][0];
    const short* Vl = &Vlds[cur][0];

    // ---- QK^T swapped: s[nt] = S[key=nt*16+lg*4+r][q=qbase+lr]
    f32x4 s[2];
    __builtin_amdgcn_s_setprio(1);
#pragma unroll
    for (int nt = 0; nt < 2; ++nt){
      f32x4 sv = (f32x4)(0.0f);
#pragma unroll
      for (int kc = 0; kc < 4; ++kc){
        bf16x8 kf = *(const bf16x8*)&Kl[(nt * 16 + lr) * 128 + ((kc * 32 + lg * 8) ^ kswz)];
        sv = MFMA16(kf, qf[kc], sv);
      }
      s[nt] = sv;
    }
    __builtin_amdgcn_s_setprio(0);

    // ---- defer-max online softmax (per-lane, THR=8 in log2 units)
    float mloc = fmaxf(fmaxf(fmaxf(s[0][0], s[0][1]), fmaxf(s[0][2], s[0][3])),
                       fmaxf(fmaxf(s[1][0], s[1][1]), fmaxf(s[1][2], s[1][3])));
    if (!__all(mloc <= mrun + 8.0f)){
      float v = mloc;
      v = fmaxf(v, __shfl_xor(v, 16));
      v = fmaxf(v, __shfl_xor(v, 32));
      float mnew = fmaxf(mrun, v);
      float sc = exp2f(mrun - mnew);
      mrun = mnew;
      lsum *= sc;
#pragma unroll
      for (int r = 0; r < 4; ++r){
        float scr = __shfl(sc, 20 * lg + r);   // lane with lr = lg*4+r
#pragma unroll
        for (int d = 0; d < 8; ++d) acc[d][r] *= scr;
      }
    }

    // ---- P = exp2(S - mrun), pack pairs
    int pk[2][2];
    {
      float p0 = exp2f(s[0][0] - mrun), p1 = exp2f(s[0][1] - mrun);
      float p2 = exp2f(s[0][2] - mrun), p3 = exp2f(s[0][3] - mrun);
      float p4 = exp2f(s[1][0] - mrun), p5 = exp2f(s[1][1] - mrun);
      float p6 = exp2f(s[1][2] - mrun), p7 = exp2f(s[1][3] - mrun);
      lsum += ((p0 + p1) + (p2 + p3)) + ((p4 + p5) + (p6 + p7));
      pk[0][0] = packbf(p0, p1); pk[0][1] = packbf(p2, p3);
      pk[1][0] = packbf(p4, p5); pk[1][1] = packbf(p6, p7);
    }

    // ---- exchange to PV A-operand layout via ds_bpermute
    i32x4 dw;
#pragma unroll
    for (int d4 = 0; d4 < 4; ++d4){
      int addr = 4 * (lr + 16 * ((2 * lg + (d4 >> 1)) & 3));
      int t0 = __builtin_amdgcn_ds_bpermute(addr, pk[0][d4 & 1]);
      int t1 = __builtin_amdgcn_ds_bpermute(addr, pk[1][d4 & 1]);
      dw[d4] = (lg >= 2) ? t1 : t0;
    }
    bf16x8 pa = __builtin_bit_cast(bf16x8, dw);

    // ---- PV: O += P @ V
    __builtin_amdgcn_s_setprio(1);
#pragma unroll
    for (int d = 0; d < 8; ++d){
      bf16x8 vf = *(const bf16x8*)&Vl[(d * 16 + lr) * 32 + ((lg * 8) ^ vswz)];
      acc[d] = MFMA16(pa, vf, acc[d]);
    }
    __builtin_amdgcn_s_setprio(0);

    __syncthreads();
    cur ^= 1;
  }

  // ---- epilogue
  const int b = bh >> 3, h = bh & 7;
  float ls = lsum;
  ls += __shfl_xor(ls, 16);
  ls += __shfl_xor(ls, 32);
  float inv = 1.0f / ls;
#pragma unroll
  for (int r = 0; r < 4; ++r){
    float invr = __shfl(inv, 20 * lg + r);
    int grow = qbase + lg * 4 + r;
    size_t base = ((size_t)b * 1024 + (size_t)h * 128 + (grow >> 3)) * 1024
                + (size_t)(grow & 7) * 128;
#pragma unroll
    for (int d = 0; d < 8; ++d)
      O[base + d * 16 + lr] = f2bf(acc[d][r] * invr);
  }
}

extern "C" void kernel_launch(void* const* d_in, const int* in_sizes, int n_in,
                              void* d_out, int out_size, void* d_ws, size_t ws_size,
                              hipStream_t stream){
  const float* motion = (const float*)d_in[0];
  const float* scene  = (const float*)d_in[1];
  const float* Wq     = (const float*)d_in[2];
  const float* bq     = (const float*)d_in[3];
  const float* Wkv    = (const float*)d_in[4];
  const float* bkv    = (const float*)d_in[5];
  const float* Wout   = (const float*)d_in[6];
  const float* bout   = (const float*)d_in[7];
  float* out = (float*)d_out;

  char* ws = (char*)d_ws;
  const size_t MB = 1024 * 1024;
  short* WqT   = (short*)(ws + 0);        // 2 MB
  short* WkvT  = (short*)(ws + 2  * MB);  // 4 MB
  short* WoutT = (short*)(ws + 6  * MB);  // 2 MB
  short* mA    = (short*)(ws + 8  * MB);  // 16 MB motion bf16 (reused as attnO)
  short* sA    = (short*)(ws + 24 * MB);  // 32 MB scene bf16
  short* Qb    = (short*)(ws + 56 * MB);  // 16 MB
  short* Kb    = (short*)(ws + 72 * MB);  // 32 MB
  short* Vtb   = (short*)(ws + 104* MB);  // 32 MB  V transposed [bh][dh][n]
  short* attnO = mA;

  const float qscale = 0.03125f * 1.44269504088896341f;  // D^-0.5 * log2(e)

  k_prep_wT<<<dim3(512),  256, 0, stream>>>(Wq,   WqT,   1024, 1024);
  k_prep_wT<<<dim3(1024), 256, 0, stream>>>(Wkv,  WkvT,  1024, 2048);
  k_prep_wT<<<dim3(512),  256, 0, stream>>>(Wout, WoutT, 1024, 1024);
  k_f2bf<<<dim3(4096), 256, 0, stream>>>(motion, mA, 1024 * 1024);
  k_f2bf<<<dim3(8192), 256, 0, stream>>>(scene,  sA, 2 * 1024 * 1024);

  k_gemm<0><<<dim3(8, 64), 256, 0, stream>>>(mA, WqT, bq, qscale, Qb, nullptr, 8192, 1024, 1024);
  k_gemmKV<<<dim3(8, 64), 512, 0, stream>>>(sA, WkvT, bkv, Kb, Vtb);
  k_attn<<<dim3(8, 128), 256, 0, stream>>>(Qb, Kb, Vtb, attnO);
  k_gemm<2><<<dim3(8, 64), 256, 0, stream>>>(attnO, WoutT, bout, 1.0f, out, nullptr, 8192, 1024, 1024);
}